// Round 5
// baseline (436.653 us; speedup 1.0000x reference)
//
#include <hip/hip_runtime.h>

// ---------------------------------------------------------------------------
// GCN graph classifier — CSR pull aggregation (src-only CSR) + bf16 gather.
//   h1 = relu(gcnconv(x, W1, b1));  h2 = relu(gcnconv(h1, W2, b2));
//   g  = mean_pool(h2, batch);      out = g @ Wl + bl
// norm factored: out[i] = dis[i]*(sum_e dis[src]*xw[src]) + dis[i]^2*xw[i]
// fill_csr (scatter-bound) fused with layer-1 GEMM (compute-bound) to overlap.
// ---------------------------------------------------------------------------

static __device__ inline ushort f32_to_bf16_rne(float f) {
    uint32_t u = __float_as_uint(f);
    uint32_t r = (u + 0x7fffu + ((u >> 16) & 1u)) >> 16;
    return (ushort)r;
}
static __device__ inline float bf_lo(uint32_t u) { return __uint_as_float(u << 16); }
static __device__ inline float bf_hi(uint32_t u) { return __uint_as_float(u & 0xffff0000u); }

// ---- degree histogram (int) ------------------------------------------------
__global__ __launch_bounds__(256) void deg_kernel(const int* __restrict__ col,
                                                  int* __restrict__ deg, int E) {
    int e = blockIdx.x * 256 + threadIdx.x;
    if (e < E) atomicAdd(&deg[col[e]], 1);
}

// ---- scan step 1: per-block sums (512 elems/block) -------------------------
__global__ __launch_bounds__(512) void block_sum_kernel(const int* __restrict__ deg,
                                                        int* __restrict__ bsums, int n) {
    __shared__ int sm[512];
    int i = blockIdx.x * 512 + threadIdx.x;
    sm[threadIdx.x] = (i < n) ? deg[i] : 0;
    __syncthreads();
    for (int s = 256; s > 0; s >>= 1) {
        if (threadIdx.x < s) sm[threadIdx.x] += sm[threadIdx.x + s];
        __syncthreads();
    }
    if (threadIdx.x == 0) bsums[blockIdx.x] = sm[0];
}

// ---- scan step 2: exclusive scan of block sums (nb <= 256, one block) ------
__global__ __launch_bounds__(256) void scan_bsums_kernel(int* __restrict__ bsums, int nb) {
    __shared__ int sm[256];
    int v = (threadIdx.x < nb) ? bsums[threadIdx.x] : 0;
    sm[threadIdx.x] = v;
    __syncthreads();
    for (int off = 1; off < 256; off <<= 1) {
        int t = (threadIdx.x >= off) ? sm[threadIdx.x - off] : 0;
        __syncthreads();
        sm[threadIdx.x] += t;
        __syncthreads();
    }
    if (threadIdx.x < nb) bsums[threadIdx.x] = sm[threadIdx.x] - v;  // exclusive
}

// ---- scan step 3: local scan + block offset -> row_ptr; also dis=rsqrt -----
__global__ __launch_bounds__(512) void scan_write_kernel(const int* __restrict__ deg,
                                                         const int* __restrict__ bsums,
                                                         int* __restrict__ rowptr,
                                                         float* __restrict__ dis,
                                                         int n, int E) {
    __shared__ int sm[512];
    int i = blockIdx.x * 512 + threadIdx.x;
    int v = (i < n) ? deg[i] : 0;
    sm[threadIdx.x] = v;
    __syncthreads();
    for (int off = 1; off < 512; off <<= 1) {
        int t = (threadIdx.x >= off) ? sm[threadIdx.x - off] : 0;
        __syncthreads();
        sm[threadIdx.x] += t;
        __syncthreads();
    }
    if (i < n) {
        rowptr[i] = bsums[blockIdx.x] + sm[threadIdx.x] - v;  // exclusive
        dis[i] = rsqrtf((float)v + 1.0f);                     // +1 = self loop
    }
    if (blockIdx.x == 0 && threadIdx.x == 0) rowptr[n] = E;
}

// ---- GEMM tile body: out_bf16[64 nodes][64] = x[64][K] @ W[K][64] ----------
template <int K>
__device__ __forceinline__ void gemm_tile_body(const float* __restrict__ x,
                                               const float* __restrict__ W,
                                               ushort* __restrict__ out, int n, int bx) {
    __shared__ float As[32][64];     // [k][node]
    __shared__ float Ws[32 * 64];    // [k][out] flat
    const int tid = threadIdx.x;
    const int tr = tid >> 4;         // 0..15 -> node quad
    const int tc = tid & 15;         // 0..15 -> out quad
    const int base = bx * 64;

    float acc[4][4];
#pragma unroll
    for (int i = 0; i < 4; ++i)
#pragma unroll
        for (int j = 0; j < 4; ++j) acc[i][j] = 0.0f;

    const int tnode = tid >> 3;          // 0..31
    const int tk4 = (tid & 7) * 4;       // 0,4,...,28

    for (int kc = 0; kc < K; kc += 32) {
        __syncthreads();
#pragma unroll
        for (int h = 0; h < 2; ++h) {
            int m = tnode + h * 32;
            int node = base + m;
            float4 v = make_float4(0.f, 0.f, 0.f, 0.f);
            if (node < n) v = *(const float4*)&x[(size_t)node * K + kc + tk4];
            As[tk4 + 0][m] = v.x; As[tk4 + 1][m] = v.y;
            As[tk4 + 2][m] = v.z; As[tk4 + 3][m] = v.w;
        }
#pragma unroll
        for (int r = 0; r < 2; ++r) {
            int o = tid * 4 + r * 1024;
            *(float4*)&Ws[o] = *(const float4*)&W[kc * 64 + o];
        }
        __syncthreads();
#pragma unroll
        for (int k = 0; k < 32; ++k) {
            float4 a = *(const float4*)&As[k][tr * 4];
            float4 b = *(const float4*)&Ws[k * 64 + tc * 4];
            const float av[4] = {a.x, a.y, a.z, a.w};
            const float bv[4] = {b.x, b.y, b.z, b.w};
#pragma unroll
            for (int i = 0; i < 4; ++i)
#pragma unroll
                for (int j = 0; j < 4; ++j)
                    acc[i][j] = fmaf(av[i], bv[j], acc[i][j]);
        }
    }
#pragma unroll
    for (int i = 0; i < 4; ++i) {
        int node = base + tr * 4 + i;
        if (node < n) {
            ushort4 st;
            st.x = f32_to_bf16_rne(acc[i][0]);
            st.y = f32_to_bf16_rne(acc[i][1]);
            st.z = f32_to_bf16_rne(acc[i][2]);
            st.w = f32_to_bf16_rne(acc[i][3]);
            *(ushort4*)&out[(size_t)node * 64 + tc * 4] = st;
        }
    }
}

// ---- standalone GEMM (layer 2) ---------------------------------------------
template <int K>
__global__ __launch_bounds__(256) void gemm_tiled(const float* __restrict__ x,
                                                  const float* __restrict__ W,
                                                  ushort* __restrict__ out, int n) {
    gemm_tile_body<K>(x, W, out, n, blockIdx.x);
}

// ---- fused: [0, nb_fill) blocks do CSR fill; rest do layer-1 GEMM ----------
// fill blocks first: fill is the long pole (scatter-bound, VALU-idle); gemm
// tiles co-schedule on the same CUs and hide under it.
template <int K>
__global__ __launch_bounds__(256) void fused_fill_gemm(
        const float* __restrict__ x, const float* __restrict__ W,
        ushort* __restrict__ out, int n, int nb_fill,
        const int* __restrict__ row, const int* __restrict__ col,
        const int* __restrict__ rowptr, int* __restrict__ fill,
        int* __restrict__ csrs, int E) {
    if ((int)blockIdx.x >= nb_fill) {
        gemm_tile_body<K>(x, W, out, n, blockIdx.x - nb_fill);
        return;
    }
    const int stride = nb_fill * 256;
    for (int e = blockIdx.x * 256 + threadIdx.x; e < E; e += stride) {
        int r = row[e], c = col[e];
        int pos = rowptr[c] + atomicAdd(&fill[c], 1);
        csrs[pos] = r;
    }
}

// ---- fused pull-aggregate + self-loop + bias + relu (bf16 gather) ----------
// wave per dst node; half-wave per edge; up to 4 edges per half in flight.
// acc = dis[i] * sum(dis[src]*xw[src]) + dis[i]^2*xw[i]
template <int OUT_BF16>
__global__ __launch_bounds__(256) void gcn_pull_kernel(const ushort* __restrict__ xw,
                                                       const int* __restrict__ csrs,
                                                       const int* __restrict__ rowptr,
                                                       const float* __restrict__ dis,
                                                       const float* __restrict__ b,
                                                       void* __restrict__ outv, int n) {
    const int lane = threadIdx.x & 63;
    const int wid = threadIdx.x >> 6;
    const int half = lane >> 5;          // 0/1 -> which edge of the pair
    const int q = lane & 31;             // feature pair index
    const float2 bb = ((const float2*)b)[q];

    for (int i = blockIdx.x * 4 + wid; i < n; i += gridDim.x * 4) {
        int s = rowptr[i], t = rowptr[i + 1];
        float di = dis[i];
        float ax = 0.0f, ay = 0.0f;
        if (half == 0) {                 // self loop: di * xw[i] (di factored out)
            uint32_t u = *(const uint32_t*)(xw + ((size_t)i << 6) + (q << 1));
            ax = di * bf_lo(u);
            ay = di * bf_hi(u);
        }
        int e = s + half;
        for (; e + 6 < t; e += 8) {      // 4 edges per half in flight
            int s0 = csrs[e], s1 = csrs[e + 2], s2 = csrs[e + 4], s3 = csrs[e + 6];
            float d0 = dis[s0], d1 = dis[s1], d2 = dis[s2], d3 = dis[s3];
            uint32_t u0 = *(const uint32_t*)(xw + ((size_t)s0 << 6) + (q << 1));
            uint32_t u1 = *(const uint32_t*)(xw + ((size_t)s1 << 6) + (q << 1));
            uint32_t u2 = *(const uint32_t*)(xw + ((size_t)s2 << 6) + (q << 1));
            uint32_t u3 = *(const uint32_t*)(xw + ((size_t)s3 << 6) + (q << 1));
            ax = fmaf(d0, bf_lo(u0), ax); ay = fmaf(d0, bf_hi(u0), ay);
            ax = fmaf(d1, bf_lo(u1), ax); ay = fmaf(d1, bf_hi(u1), ay);
            ax = fmaf(d2, bf_lo(u2), ax); ay = fmaf(d2, bf_hi(u2), ay);
            ax = fmaf(d3, bf_lo(u3), ax); ay = fmaf(d3, bf_hi(u3), ay);
        }
        for (; e + 2 < t; e += 4) {      // 2-deep
            int s0 = csrs[e], s1 = csrs[e + 2];
            float d0 = dis[s0], d1 = dis[s1];
            uint32_t u0 = *(const uint32_t*)(xw + ((size_t)s0 << 6) + (q << 1));
            uint32_t u1 = *(const uint32_t*)(xw + ((size_t)s1 << 6) + (q << 1));
            ax = fmaf(d0, bf_lo(u0), ax); ay = fmaf(d0, bf_hi(u0), ay);
            ax = fmaf(d1, bf_lo(u1), ax); ay = fmaf(d1, bf_hi(u1), ay);
        }
        for (; e < t; e += 2) {          // tail
            int s0 = csrs[e];
            float d0 = dis[s0];
            uint32_t u0 = *(const uint32_t*)(xw + ((size_t)s0 << 6) + (q << 1));
            ax = fmaf(d0, bf_lo(u0), ax); ay = fmaf(d0, bf_hi(u0), ay);
        }
        // combine the two halves
        ax += __shfl_xor(ax, 32);
        ay += __shfl_xor(ay, 32);
        if (half == 0) {
            float v0 = fmaxf(fmaf(di, ax, bb.x), 0.0f);
            float v1 = fmaxf(fmaf(di, ay, bb.y), 0.0f);
            if (OUT_BF16) {
                ushort2 st = make_ushort2(f32_to_bf16_rne(v0), f32_to_bf16_rne(v1));
                *(ushort2*)((ushort*)outv + ((size_t)i << 6) + (q << 1)) = st;
            } else {
                *(float2*)((float*)outv + ((size_t)i << 6) + (q << 1)) = make_float2(v0, v1);
            }
        }
    }
}

// ---- segmented mean-pool (batch sorted, bf16 input): 32 nodes/wave ---------
__global__ __launch_bounds__(256) void pool_kernel(const ushort* __restrict__ h,
                                                   const int* __restrict__ batch,
                                                   float* __restrict__ pool,
                                                   float* __restrict__ cnt, int n) {
    const int lane = threadIdx.x & 63;
    const int wid = threadIdx.x >> 6;
    const int start = (blockIdx.x * 4 + wid) * 32;
    const int end = min(start + 32, n);
    if (start >= end) return;
    int gcur = batch[start];
    float acc = 0.0f;
    int c = 0;
    for (int i = start; i < end; ++i) {
        int g = batch[i];           // wave-uniform
        if (g != gcur) {
            atomicAdd(&pool[gcur * 64 + lane], acc);
            if (lane == 0) atomicAdd(&cnt[gcur], (float)c);
            acc = 0.0f; c = 0; gcur = g;
        }
        acc += __uint_as_float((uint32_t)h[(size_t)i * 64 + lane] << 16);
        ++c;
    }
    atomicAdd(&pool[gcur * 64 + lane], acc);
    if (lane == 0) atomicAdd(&cnt[gcur], (float)c);
}

// ---- final: out[64][10] = (pool/cnt) @ Wl + bl -----------------------------
__global__ __launch_bounds__(640) void final_kernel(const float* __restrict__ pool,
                                                    const float* __restrict__ cnt,
                                                    const float* __restrict__ Wl,
                                                    const float* __restrict__ bl,
                                                    float* __restrict__ out) {
    int tid = threadIdx.x;            // 640 = 64 graphs * 10 outputs
    int g = tid / 10, o = tid % 10;
    float inv = 1.0f / fmaxf(cnt[g], 1.0f);
    float acc = 0.0f;
#pragma unroll
    for (int l = 0; l < 64; ++l)
        acc = fmaf(pool[g * 64 + l] * inv, Wl[l * 10 + o], acc);
    out[tid] = acc + bl[o];
}

extern "C" void kernel_launch(void* const* d_in, const int* in_sizes, int n_in,
                              void* d_out, int out_size, void* d_ws, size_t ws_size,
                              hipStream_t stream) {
    const float* x  = (const float*)d_in[0];
    const float* W1 = (const float*)d_in[1];
    const float* b1 = (const float*)d_in[2];
    const float* W2 = (const float*)d_in[3];
    const float* b2 = (const float*)d_in[4];
    const float* Wl = (const float*)d_in[5];
    const float* bl = (const float*)d_in[6];
    const int*   ei = (const int*)d_in[7];    // [2, E] -> row = ei, col = ei + E
    const int*   batch = (const int*)d_in[8];
    float* out = (float*)d_out;

    const int n = in_sizes[8];           // 100000 nodes
    const int E = in_sizes[7] / 2;       // 1600000 edges
    const int F = 64;

    const int* row = ei;
    const int* col = ei + E;

    // ---- workspace layout (256B-aligned chunks) ----
    char* p = (char*)d_ws;
    auto alloc = [&](size_t bytes) {
        char* r = p;
        p += (bytes + 255) & ~(size_t)255;
        return r;
    };
    int*    degi   = (int*)   alloc((size_t)n * 4);          // deg, reused as fill
    int*    rowptr = (int*)   alloc((size_t)(n + 1) * 4);
    int*    bsums  = (int*)   alloc(256 * 4);
    float*  dis    = (float*) alloc((size_t)n * 4);
    int*    csrs   = (int*)   alloc((size_t)E * 4);          // src-only CSR
    ushort* xwB    = (ushort*)alloc((size_t)n * F * 2);      // bf16 gather table
    float*  B      = (float*) alloc((size_t)n * F * 4);      // h1 f32 / h2 bf16 reuse
    float*  pool   = (float*) alloc(64 * 64 * 4);
    float*  cnt    = (float*) alloc(64 * 4);

    const int nb_edge = (E + 255) / 256;
    const int nb_scan = (n + 511) / 512;     // 196 for n=100000
    const int nb_gemm = (n + 63) / 64;       // 1563
    const int nb_fill = 1024;

    // ---- CSR build prologue ----
    hipMemsetAsync(degi, 0, (size_t)n * 4, stream);
    deg_kernel<<<nb_edge, 256, 0, stream>>>(col, degi, E);
    block_sum_kernel<<<nb_scan, 512, 0, stream>>>(degi, bsums, n);
    scan_bsums_kernel<<<1, 256, 0, stream>>>(bsums, nb_scan);
    scan_write_kernel<<<nb_scan, 512, 0, stream>>>(degi, bsums, rowptr, dis, n, E);
    hipMemsetAsync(degi, 0, (size_t)n * 4, stream);          // reuse as fill counters

    // ---- CSR fill || layer-1 GEMM (independent; co-scheduled) ----
    fused_fill_gemm<128><<<nb_fill + nb_gemm, 256, 0, stream>>>(
        x, W1, xwB, n, nb_fill, row, col, rowptr, degi, csrs, E);

    // ---- layer 1 aggregate ----
    gcn_pull_kernel<0><<<2048, 256, 0, stream>>>(xwB, csrs, rowptr, dis, b1, B, n);

    // ---- layer 2 ----
    gemm_tiled<64><<<nb_gemm, 256, 0, stream>>>(B, W2, xwB, n);
    gcn_pull_kernel<1><<<2048, 256, 0, stream>>>(xwB, csrs, rowptr, dis, b2, B, n);

    // ---- pool + classifier ----
    hipMemsetAsync(pool, 0, (64 * 64 + 64) * sizeof(float), stream);
    pool_kernel<<<(n + 127) / 128, 256, 0, stream>>>((const ushort*)B, batch, pool, cnt, n);
    final_kernel<<<1, 640, 0, stream>>>(pool, cnt, Wl, bl, out);
}